// Round 10
// baseline (383.546 us; speedup 1.0000x reference)
//
#include <hip/hip_runtime.h>
#include <math.h>

#define N_NODES 64000
#define N_EDGES 1048576
#define NB 1000
#define NG 64
#define NOUT 64
#define FC_SPLIT 500      // 500 x 256 = 128000 K-rows
#define BK_CAP 18000      // per-graph edge bucket capacity (mean 16384, +12.7 sigma)

typedef __attribute__((ext_vector_type(8))) short bfrag;   // 8 bf16 = 4 VGPRs
typedef __attribute__((ext_vector_type(4))) float f32x4;
typedef __attribute__((ext_vector_type(2))) float f32x2;

__device__ inline float bflo(unsigned int u) {
    union { unsigned int i; float f; } x; x.i = u << 16; return x.f;
}
__device__ inline float bfhi(unsigned int u) {
    union { unsigned int i; float f; } x; x.i = u & 0xffff0000u; return x.f;
}
__device__ inline f32x2 upk(unsigned int u) {   // {lo,hi} bf16 pair -> f32x2 (v_pk_add friendly)
    f32x2 r; r.x = bflo(u); r.y = bfhi(u); return r;
}
__device__ inline unsigned short f2bf(float f) {   // round-to-nearest-even
    union { float f; unsigned int i; } x; x.f = f;
    return (unsigned short)((x.i + 0x7FFFu + ((x.i >> 16) & 1u)) >> 16);
}
// fast tanh: 1 - 2/(e^{2x}+1). Saturates correctly; ~1e-6 abs error (<< bf16 quantization).
__device__ inline float tanh_fast(float x) {
    float e = __expf(2.0f * x);
    return fmaf(-2.0f, __builtin_amdgcn_rcpf(e + 1.0f), 1.0f);
}
// XOR swizzles: 16B-group g of row -> physical group. Involutions (swz(swz(g))=g).
__device__ inline int swz32(int row, int g) { return g ^ (row & 7) ^ (g >> 3); }  // 32 groups (256-short rows)
__device__ inline int swz16(int row, int g) { return g ^ (row & 7) ^ (g >> 3); }  // 16 groups (128-short rows)

// ---------------- CSR build, graph-bucketed ----------------

__global__ __launch_bounds__(256) void k_bucket(const int* __restrict__ src,
                                                const int* __restrict__ dst,
                                                int* __restrict__ gcnt,
                                                unsigned int* __restrict__ bucket) {
    __shared__ int lcnt[64];
    __shared__ int lbase[64];
    __shared__ int lcur[64];
    int t = threadIdx.x;
    int e0 = blockIdx.x * 4096;
    if (t < 64) { lcnt[t] = 0; lcur[t] = 0; }
    __syncthreads();
    for (int i = t; i < 4096; i += 256) {
        int d = dst[e0 + i];
        int g = d / NB;
        atomicAdd(&lcnt[g], 1);
    }
    __syncthreads();
    if (t < 64) lbase[t] = atomicAdd(&gcnt[t], lcnt[t]);
    __syncthreads();
    for (int i = t; i < 4096; i += 256) {
        int d = dst[e0 + i];
        int s = src[e0 + i];
        int g = d / NB;
        int pos = atomicAdd(&lcur[g], 1);
        unsigned int packed = ((unsigned int)(d - g * NB) << 10) | (unsigned int)(s - g * NB);
        bucket[(size_t)g * BK_CAP + lbase[g] + pos] = packed;
    }
}

__global__ __launch_bounds__(1024) void k_build(const int* __restrict__ gcnt,
                                                const unsigned int* __restrict__ bucket,
                                                int* __restrict__ rowptr,
                                                int* __restrict__ rowend,
                                                float* __restrict__ dinv,
                                                unsigned short* __restrict__ colp) {
    __shared__ int ind[1024];
    __shared__ int tmp[1024];
    int t = threadIdx.x;
    int g = blockIdx.x;
    int cnt = gcnt[g];
    size_t base = (size_t)g * BK_CAP;
    ind[t] = 0;
    __syncthreads();
    for (int i = t; i < cnt; i += 1024) {
        unsigned int p = bucket[base + i];
        atomicAdd(&ind[p >> 10], 1);
    }
    __syncthreads();
    int deg = ind[t];
    if (t < NB) dinv[g * NB + t] = rsqrtf((float)(deg + 1));
    tmp[t] = deg;
    __syncthreads();
    for (int off = 1; off < 1024; off <<= 1) {
        int o = (t >= off) ? tmp[t - off] : 0;
        __syncthreads();
        tmp[t] += o;
        __syncthreads();
    }
    int excl = tmp[t] - deg;
    if (t < NB) {
        rowptr[g * NB + t] = (int)base + excl;
        rowend[g * NB + t] = (int)base + excl + deg;
    }
    ind[t] = excl;           // reuse as cursor
    __syncthreads();
    for (int i = t; i < cnt; i += 1024) {
        unsigned int p = bucket[base + i];
        int dl = p >> 10;
        int pos = atomicAdd(&ind[dl], 1);
        colp[base + pos] = (unsigned short)(p & 1023u);
    }
}

// ---------------- casts ----------------

__global__ void k_cast_scale(const float* __restrict__ in, const float* __restrict__ dinv,
                             unsigned short* __restrict__ out) {
    int i = (blockIdx.x * blockDim.x + threadIdx.x) * 4;
    float d = dinv[i >> 7];
    float4 v = *(const float4*)(in + i);
    union { unsigned short s[4]; uint2 u; } o;
    o.s[0] = f2bf(v.x * d); o.s[1] = f2bf(v.y * d);
    o.s[2] = f2bf(v.z * d); o.s[3] = f2bf(v.w * d);
    *(uint2*)(out + i) = o.u;
}

// all three W[K][N] fp32 -> Wt[N][K] bf16 transposes in one launch (512 blocks)
__global__ void k_wt_all(const float* __restrict__ W1, const float* __restrict__ W2,
                         const float* __restrict__ W3, unsigned short* __restrict__ W1t,
                         unsigned short* __restrict__ W2t, unsigned short* __restrict__ W3t) {
    int i = blockIdx.x * 256 + threadIdx.x;
    if (i < 32768) {                     // W1: 128x256
        int n = i / 128, k = i % 128;
        W1t[i] = f2bf(W1[k * 256 + n]);
    } else if (i < 98304) {              // W2: 256x256
        int j = i - 32768;
        int n = j / 256, k = j % 256;
        W2t[j] = f2bf(W2[k * 256 + n]);
    } else {                             // W3: 256x128
        int j = i - 98304;
        int n = j / 256, k = j % 256;
        W3t[j] = f2bf(W3[k * 128 + n]);
    }
}

// ---------------- standalone pull aggregation (layer 3 only) ----------------
// R7-proven: graph->XCD pinned blocks, readlane-broadcast gathers, tiered batching.

template <int H, bool TANH>
__global__ __launch_bounds__(256) void k_agg(const unsigned short* __restrict__ hs,
                                             unsigned short* __restrict__ op,
                                             const int* __restrict__ rowptr,
                                             const int* __restrict__ rowend,
                                             const unsigned short* __restrict__ col,
                                             const float* __restrict__ dinv,
                                             const float* __restrict__ bias) {
    constexpr int VEC = H / 64;
    int lane = threadIdx.x & 63;
    int b = blockIdx.x;
    int c = b & 7;
    int j = b >> 3;
    int g = c + 8 * (j / 250);
    int chunk = j % 250;
    int v = g * NB + chunk * 4 + (threadIdx.x >> 6);
    const unsigned short* gb = hs + (size_t)g * NB * H;
    f32x2 a0, a1;
    a0 = f32x2{0.f, 0.f}; a1 = f32x2{0.f, 0.f};
    {
        const unsigned short* r = hs + (size_t)v * H + lane * VEC;
        if (VEC == 2) {
            a0 = upk(*(const unsigned int*)r);
        } else {
            uint2 u = *(const uint2*)r;
            a0 = upk(u.x); a1 = upk(u.y);
        }
    }
    int beg = rowptr[v], end = rowend[v];
    for (int e0 = beg; e0 < end; e0 += 64) {
        int me = e0 + lane;
        int s = (me < end) ? (int)col[me] : 0;
        int cnt = min(64, end - e0);
        int i = 0;
        for (; i + 8 <= cnt; i += 8) {
            int sx[8];
#pragma unroll
            for (int q = 0; q < 8; ++q) sx[q] = __builtin_amdgcn_readlane(s, i + q);
            if (VEC == 2) {
                unsigned int u[8];
#pragma unroll
                for (int q = 0; q < 8; ++q)
                    u[q] = *(const unsigned int*)(gb + (size_t)sx[q] * H + lane * 2);
#pragma unroll
                for (int q = 0; q < 8; ++q) a0 += upk(u[q]);
            } else {
                uint2 u[8];
#pragma unroll
                for (int q = 0; q < 8; ++q)
                    u[q] = *(const uint2*)(gb + (size_t)sx[q] * H + lane * 4);
#pragma unroll
                for (int q = 0; q < 8; ++q) { a0 += upk(u[q].x); a1 += upk(u[q].y); }
            }
        }
        for (; i + 4 <= cnt; i += 4) {
            int sx[4];
#pragma unroll
            for (int q = 0; q < 4; ++q) sx[q] = __builtin_amdgcn_readlane(s, i + q);
            if (VEC == 2) {
                unsigned int u[4];
#pragma unroll
                for (int q = 0; q < 4; ++q)
                    u[q] = *(const unsigned int*)(gb + (size_t)sx[q] * H + lane * 2);
#pragma unroll
                for (int q = 0; q < 4; ++q) a0 += upk(u[q]);
            } else {
                uint2 u[4];
#pragma unroll
                for (int q = 0; q < 4; ++q)
                    u[q] = *(const uint2*)(gb + (size_t)sx[q] * H + lane * 4);
#pragma unroll
                for (int q = 0; q < 4; ++q) { a0 += upk(u[q].x); a1 += upk(u[q].y); }
            }
        }
        for (; i < cnt; ++i) {
            int ss = __builtin_amdgcn_readlane(s, i);
            if (VEC == 2) {
                a0 += upk(*(const unsigned int*)(gb + (size_t)ss * H + lane * 2));
            } else {
                uint2 u = *(const uint2*)(gb + (size_t)ss * H + lane * 4);
                a0 += upk(u.x); a1 += upk(u.y);
            }
        }
    }
    float dv = dinv[v];
    float acc[4];
    acc[0] = a0.x; acc[1] = a0.y;
    if (VEC == 4) { acc[2] = a1.x; acc[3] = a1.y; }
    if (TANH) {
#pragma unroll
        for (int q = 0; q < VEC; ++q) acc[q] = tanh_fast(acc[q] * dv + bias[lane * VEC + q]);
    } else {
#pragma unroll
        for (int q = 0; q < VEC; ++q) acc[q] *= dv;
    }
    unsigned short* o = op + (size_t)v * H + lane * VEC;
    if (VEC == 2) {
        union { unsigned short s[2]; unsigned int u; } pk;
        pk.s[0] = f2bf(acc[0]); pk.s[1] = f2bf(acc[1]);
        *(unsigned int*)o = pk.u;
    } else {
        union { unsigned short s[4]; uint2 u; } pk;
        pk.s[0] = f2bf(acc[0]); pk.s[1] = f2bf(acc[1]);
        pk.s[2] = f2bf(acc[2]); pk.s[3] = f2bf(acc[3]);
        *(uint2*)o = pk.u;
    }
}

// ---- fused-kernel block mapping: 32 blocks/graph, graph->XCD pinned ----
// b = xcd + 8*j; g = xcd + 8*(j>>5); chunk = j&31. All blocks of graph g have
// b == g (mod 8) -> same XCD -> graph slice stays in one L2. chunk 31: 8 rows.
// __launch_bounds__(256,8): 8 blocks/CU (grid 2048 = 256CU x 8 -> fully
// co-resident, 32 waves/CU). VGPR<=64 required; R9 measured 56. LDS 8x16KB=128KB.

// ---------------- FUSED agg(H=128) + layer-1 GEMM ----------------

__global__ __launch_bounds__(256, 8) void k_aggemm1(const unsigned short* __restrict__ P0,
                                                    const int* __restrict__ rowptr,
                                                    const int* __restrict__ rowend,
                                                    const unsigned short* __restrict__ col,
                                                    const float* __restrict__ dinv,
                                                    const unsigned short* __restrict__ W1t,
                                                    const float* __restrict__ b1,
                                                    unsigned short* __restrict__ C) {
    constexpr int K = 128, N = 256;
    __shared__ unsigned short at[32 * 128];   // 8 KB, swizzled A-tile
    int t = threadIdx.x;
    int w = t >> 6, l = t & 63;
    int lm = l & 15, lq = l >> 4;
    int n0 = w * 64;
    int row0 = lq * 4;
    int b = blockIdx.x;
    int xcd = b & 7, jj = b >> 3;
    int g = xcd + 8 * (jj >> 5);
    int chunk = jj & 31;
    int m0 = g * NB + chunk * 32;             // first node of tile
    int nvalid = min(32, NB - chunk * 32);    // 8 for chunk==31
    const unsigned short* gb = P0 + (size_t)g * NB * K;

    // ---- phase 1: gather 8 rows per wave (wave-uniform validity) ----
    for (int r = 0; r < 8; ++r) {
        int row = w * 8 + r;
        unsigned int* slot = (unsigned int*)&at[row * 128 + swz16(row, l >> 2) * 8 + (l & 3) * 2];
        if (row < nvalid) {
            int v = m0 + row;
            f32x2 a0 = upk(*(const unsigned int*)(P0 + (size_t)v * K + l * 2));  // self
            int beg = rowptr[v], end = rowend[v];
            for (int e0 = beg; e0 < end; e0 += 64) {
                int me = e0 + l;
                int s = (me < end) ? (int)col[me] : 0;
                int cnt = min(64, end - e0);
                int i = 0;
                for (; i + 8 <= cnt; i += 8) {
                    int sx[8];
#pragma unroll
                    for (int q = 0; q < 8; ++q) sx[q] = __builtin_amdgcn_readlane(s, i + q);
                    unsigned int u[8];
#pragma unroll
                    for (int q = 0; q < 8; ++q)
                        u[q] = *(const unsigned int*)(gb + (size_t)sx[q] * K + l * 2);
#pragma unroll
                    for (int q = 0; q < 8; ++q) a0 += upk(u[q]);
                }
                for (; i + 4 <= cnt; i += 4) {
                    int sx[4];
#pragma unroll
                    for (int q = 0; q < 4; ++q) sx[q] = __builtin_amdgcn_readlane(s, i + q);
                    unsigned int u[4];
#pragma unroll
                    for (int q = 0; q < 4; ++q)
                        u[q] = *(const unsigned int*)(gb + (size_t)sx[q] * K + l * 2);
#pragma unroll
                    for (int q = 0; q < 4; ++q) a0 += upk(u[q]);
                }
                for (; i < cnt; ++i) {
                    int ss = __builtin_amdgcn_readlane(s, i);
                    a0 += upk(*(const unsigned int*)(gb + (size_t)ss * K + l * 2));
                }
            }
            float dv = dinv[v];
            union { unsigned short s2[2]; unsigned int u; } pk;
            pk.s2[0] = f2bf(a0.x * dv); pk.s2[1] = f2bf(a0.y * dv);
            *slot = pk.u;
        } else {
            *slot = 0u;
        }
    }
    __syncthreads();

    // ---- phase 2: C = tanh(A @ W1 + b1) * dinv, W1 streamed (double-buffered) ----
    f32x4 acc[2][4] = {};
    const unsigned short* Bb = W1t + (size_t)(n0 + lm) * K + lq * 8;
    bfrag bfb[2][4];
#pragma unroll
    for (int j = 0; j < 4; ++j) bfb[0][j] = *(const bfrag*)(Bb + (size_t)j * 16 * K);
#pragma unroll
    for (int it = 0; it < K / 32; ++it) {
        int ks = it * 32, cur = it & 1;
        if (it + 1 < K / 32) {
#pragma unroll
            for (int j = 0; j < 4; ++j)
                bfb[cur ^ 1][j] = *(const bfrag*)(Bb + (size_t)j * 16 * K + ks + 32);
        }
        bfrag af[2];
        int gidx = it * 4 + lq;
#pragma unroll
        for (int i = 0; i < 2; ++i) {
            int row = i * 16 + lm;
            af[i] = *(const bfrag*)&at[row * 128 + swz16(row, gidx) * 8];
        }
#pragma unroll
        for (int i = 0; i < 2; ++i)
#pragma unroll
            for (int j = 0; j < 4; ++j)
                acc[i][j] = __builtin_amdgcn_mfma_f32_16x16x32_bf16(af[i], bfb[cur][j], acc[i][j], 0, 0, 0);
    }
    float bj[4];
#pragma unroll
    for (int j = 0; j < 4; ++j) bj[j] = b1[n0 + j * 16 + lm];
#pragma unroll
    for (int i = 0; i < 2; ++i)
#pragma unroll
        for (int r = 0; r < 4; ++r) {
            int rr = i * 16 + row0 + r;
            if (rr < nvalid) {
                float dv = dinv[m0 + rr];
#pragma unroll
                for (int j = 0; j < 4; ++j) {
                    float v = tanh_fast(acc[i][j][r] + bj[j]) * dv;
                    C[(size_t)(m0 + rr) * N + n0 + j * 16 + lm] = f2bf(v);
                }
            }
        }
}

// ---------------- FUSED agg(H=256) + layers 2+3 GEMM ----------------

__global__ __launch_bounds__(256, 8) void k_aggemm23(const unsigned short* __restrict__ P2,
                                                     const int* __restrict__ rowptr,
                                                     const int* __restrict__ rowend,
                                                     const unsigned short* __restrict__ col,
                                                     const float* __restrict__ dinv,
                                                     const unsigned short* __restrict__ W2t,
                                                     const float* __restrict__ b2,
                                                     const unsigned short* __restrict__ W3t,
                                                     unsigned short* __restrict__ C) {
    constexpr int K = 256, N3 = 128;
    __shared__ unsigned short at[32 * 256];   // 16 KB, swizzled; A-tile then C2
    int t = threadIdx.x;
    int w = t >> 6, l = t & 63;
    int lm = l & 15, lq = l >> 4;
    int n0 = w * 64;
    int row0 = lq * 4;
    int b = blockIdx.x;
    int xcd = b & 7, jj = b >> 3;
    int g = xcd + 8 * (jj >> 5);
    int chunk = jj & 31;
    int m0 = g * NB + chunk * 32;
    int nvalid = min(32, NB - chunk * 32);
    const unsigned short* gb = P2 + (size_t)g * NB * K;

    // ---- phase 1: gather 8 rows per wave (uint2 per lane) ----
    for (int r = 0; r < 8; ++r) {
        int row = w * 8 + r;
        uint2* slot = (uint2*)&at[row * 256 + swz32(row, l >> 1) * 8 + (l & 1) * 4];
        if (row < nvalid) {
            int v = m0 + row;
            f32x2 a0, a1;
            {
                uint2 u = *(const uint2*)(P2 + (size_t)v * K + l * 4);   // self
                a0 = upk(u.x); a1 = upk(u.y);
            }
            int beg = rowptr[v], end = rowend[v];
            for (int e0 = beg; e0 < end; e0 += 64) {
                int me = e0 + l;
                int s = (me < end) ? (int)col[me] : 0;
                int cnt = min(64, end - e0);
                int i = 0;
                for (; i + 8 <= cnt; i += 8) {
                    int sx[8];
#pragma unroll
                    for (int q = 0; q < 8; ++q) sx[q] = __builtin_amdgcn_readlane(s, i + q);
                    uint2 u[8];
#pragma unroll
                    for (int q = 0; q < 8; ++q)
                        u[q] = *(const uint2*)(gb + (size_t)sx[q] * K + l * 4);
#pragma unroll
                    for (int q = 0; q < 8; ++q) { a0 += upk(u[q].x); a1 += upk(u[q].y); }
                }
                for (; i + 4 <= cnt; i += 4) {
                    int sx[4];
#pragma unroll
                    for (int q = 0; q < 4; ++q) sx[q] = __builtin_amdgcn_readlane(s, i + q);
                    uint2 u[4];
#pragma unroll
                    for (int q = 0; q < 4; ++q)
                        u[q] = *(const uint2*)(gb + (size_t)sx[q] * K + l * 4);
#pragma unroll
                    for (int q = 0; q < 4; ++q) { a0 += upk(u[q].x); a1 += upk(u[q].y); }
                }
                for (; i < cnt; ++i) {
                    int ss = __builtin_amdgcn_readlane(s, i);
                    uint2 u = *(const uint2*)(gb + (size_t)ss * K + l * 4);
                    a0 += upk(u.x); a1 += upk(u.y);
                }
            }
            float dv = dinv[v];
            union { unsigned short s4[4]; uint2 u; } pk;
            pk.s4[0] = f2bf(a0.x * dv); pk.s4[1] = f2bf(a0.y * dv);
            pk.s4[2] = f2bf(a1.x * dv); pk.s4[3] = f2bf(a1.y * dv);
            *slot = pk.u;
        } else {
            uint2 z; z.x = 0u; z.y = 0u;
            *slot = z;
        }
    }
    __syncthreads();

    // ---- stage 1: C2 = tanh(A @ W2 + b2), W2 streamed (double-buffered) ----
    f32x4 acc[2][4] = {};
    {
        const unsigned short* Bb = W2t + (size_t)(n0 + lm) * K + lq * 8;
        bfrag bfb[2][4];
#pragma unroll
        for (int j = 0; j < 4; ++j) bfb[0][j] = *(const bfrag*)(Bb + (size_t)j * 16 * K);
#pragma unroll
        for (int it = 0; it < K / 32; ++it) {
            int ks = it * 32, cur = it & 1;
            if (it + 1 < K / 32) {
#pragma unroll
                for (int j = 0; j < 4; ++j)
                    bfb[cur ^ 1][j] = *(const bfrag*)(Bb + (size_t)j * 16 * K + ks + 32);
            }
            bfrag af[2];
            int gidx = it * 4 + lq;
#pragma unroll
            for (int i = 0; i < 2; ++i) {
                int row = i * 16 + lm;
                af[i] = *(const bfrag*)&at[row * 256 + swz32(row, gidx) * 8];
            }
#pragma unroll
            for (int i = 0; i < 2; ++i)
#pragma unroll
                for (int j = 0; j < 4; ++j)
                    acc[i][j] = __builtin_amdgcn_mfma_f32_16x16x32_bf16(af[i], bfb[cur][j], acc[i][j], 0, 0, 0);
        }
    }
    __syncthreads();   // all stage-1 A-reads done; safe to overwrite with C2
    {
        float bj[4];
#pragma unroll
        for (int j = 0; j < 4; ++j) bj[j] = b2[n0 + j * 16 + lm];
#pragma unroll
        for (int i = 0; i < 2; ++i)
#pragma unroll
            for (int j = 0; j < 4; ++j) {
                int colb = n0 + j * 16 + lm;
                int gidx = colb >> 3, off = colb & 7;
#pragma unroll
                for (int r = 0; r < 4; ++r) {
                    int row = i * 16 + row0 + r;
                    at[row * 256 + swz32(row, gidx) * 8 + off] =
                        f2bf(tanh_fast(acc[i][j][r] + bj[j]));
                }
            }
    }
    __syncthreads();
    // ---- stage 2: C3 = (C2 @ W3) * dinv, W3 streamed (prefetch-1) ----
    {
        f32x4 acc2[2][2] = {};
        int n3 = w * 32;
        const unsigned short* Bb = W3t + (size_t)(n3 + lm) * K + lq * 8;
        bfrag bfb[2][2];
#pragma unroll
        for (int j = 0; j < 2; ++j) bfb[0][j] = *(const bfrag*)(Bb + (size_t)j * 16 * K);
#pragma unroll
        for (int it = 0; it < K / 32; ++it) {
            int ks = it * 32, cur = it & 1;
            if (it + 1 < K / 32) {
#pragma unroll
                for (int j = 0; j < 2; ++j)
                    bfb[cur ^ 1][j] = *(const bfrag*)(Bb + (size_t)j * 16 * K + ks + 32);
            }
            bfrag af[2];
            int gidx = it * 4 + lq;
#pragma unroll
            for (int i = 0; i < 2; ++i) {
                int row = i * 16 + lm;
                af[i] = *(const bfrag*)&at[row * 256 + swz32(row, gidx) * 8];
            }
#pragma unroll
            for (int i = 0; i < 2; ++i)
#pragma unroll
                for (int j = 0; j < 2; ++j)
                    acc2[i][j] = __builtin_amdgcn_mfma_f32_16x16x32_bf16(af[i], bfb[cur][j], acc2[i][j], 0, 0, 0);
        }
        int n3b = w * 32;
#pragma unroll
        for (int i = 0; i < 2; ++i)
#pragma unroll
            for (int r = 0; r < 4; ++r) {
                int rr = i * 16 + row0 + r;
                if (rr < nvalid) {
                    float dv = dinv[m0 + rr];
#pragma unroll
                    for (int j = 0; j < 2; ++j)
                        C[(size_t)(m0 + rr) * N3 + n3b + j * 16 + lm] =
                            f2bf(acc2[i][j][r] * dv);
                }
            }
    }
}

// ---------------- final FC: out[64,64] = h[64,128000](bf16) @ Wfc[128000,64](f32) + bfc

__global__ void k_fc(const unsigned short* __restrict__ A, const float* __restrict__ B,
                     float* __restrict__ part) {
    __shared__ float As[16][68];
    __shared__ float Bs[16][68];
    const int KROW = NB * 128;         // 128000
    int t = threadIdx.x;
    int tx = t & 15, ty = t >> 4;
    int k0b = blockIdx.x * 256;
    float acc[4][4] = {};
    for (int k0 = k0b; k0 < k0b + 256; k0 += 16) {
        int arow = t >> 2, ak = (t & 3) << 2;
        uint2 ua = *(const uint2*)(A + (size_t)arow * KROW + k0 + ak);
        As[ak + 0][arow] = bflo(ua.x);
        As[ak + 1][arow] = bfhi(ua.x);
        As[ak + 2][arow] = bflo(ua.y);
        As[ak + 3][arow] = bfhi(ua.y);
        int bk = t >> 4, bn4 = (t & 15) << 2;
        *(float4*)&Bs[bk][bn4] = *(const float4*)(B + (size_t)(k0 + bk) * NOUT + bn4);
        __syncthreads();
#pragma unroll
        for (int kk = 0; kk < 16; ++kk) {
            float4 a = *(const float4*)&As[kk][ty << 2];
            float4 b = *(const float4*)&Bs[kk][tx << 2];
            acc[0][0] += a.x * b.x; acc[0][1] += a.x * b.y; acc[0][2] += a.x * b.z; acc[0][3] += a.x * b.w;
            acc[1][0] += a.y * b.x; acc[1][1] += a.y * b.y; acc[1][2] += a.y * b.z; acc[1][3] += a.y * b.w;
            acc[2][0] += a.z * b.x; acc[2][1] += a.z * b.y; acc[2][2] += a.z * b.z; acc[2][3] += a.z * b.w;
            acc[3][0] += a.w * b.x; acc[3][1] += a.w * b.y; acc[3][2] += a.w * b.z; acc[3][3] += a.w * b.w;
        }
        __syncthreads();
    }
    float* po = part + (size_t)blockIdx.x * (NG * NOUT);
#pragma unroll
    for (int i = 0; i < 4; ++i) {
        float4 r;
        r.x = acc[i][0]; r.y = acc[i][1]; r.z = acc[i][2]; r.w = acc[i][3];
        *(float4*)&po[((ty << 2) + i) * NOUT + (tx << 2)] = r;
    }
}

__global__ void k_fc_reduce(const float* __restrict__ part, const float* __restrict__ bfc,
                            float* __restrict__ out) {
    int i = blockIdx.x * blockDim.x + threadIdx.x;   // 4096 threads
    float s = bfc[i & 63];
    for (int b = 0; b < FC_SPLIT; ++b) s += part[(size_t)b * (NG * NOUT) + i];
    out[i] = s;
}

// ---------------- driver ----------------

static inline size_t align256(size_t x) { return (x + 255) & ~(size_t)255; }

extern "C" void kernel_launch(void* const* d_in, const int* in_sizes, int n_in,
                              void* d_out, int out_size, void* d_ws, size_t ws_size,
                              hipStream_t stream) {
    const float* x   = (const float*)d_in[0];
    const int*   ei  = (const int*)d_in[1];
    const int*   src = ei;
    const int*   dst = ei + N_EDGES;
    const float* W1  = (const float*)d_in[3];
    const float* b1  = (const float*)d_in[4];
    const float* W2  = (const float*)d_in[5];
    const float* b2  = (const float*)d_in[6];
    const float* W3  = (const float*)d_in[7];
    const float* b3  = (const float*)d_in[8];
    const float* Wfc = (const float*)d_in[9];
    const float* bfc = (const float*)d_in[10];
    float* out = (float*)d_out;

    char* w = (char*)d_ws;
    unsigned short* P0 = (unsigned short*)w; w += align256((size_t)N_NODES * 256 * 2);
    unsigned short* P1 = (unsigned short*)w; w += align256((size_t)N_NODES * 256 * 2);
    unsigned short* P2 = (unsigned short*)w; w += align256((size_t)N_NODES * 256 * 2);
    int* rowptr = (int*)w;      w += align256((size_t)N_NODES * 4);
    int* rowend = (int*)w;      w += align256((size_t)N_NODES * 4);
    float* dinv = (float*)w;    w += align256((size_t)N_NODES * 4);
    int* gcnt = (int*)w;        w += align256((size_t)NG * 4);
    unsigned int* bucket = (unsigned int*)w; w += align256((size_t)NG * BK_CAP * 4);
    unsigned short* colp = (unsigned short*)w; w += align256((size_t)NG * BK_CAP * 2);
    float* fcpart = (float*)w;  w += align256((size_t)FC_SPLIT * NG * NOUT * 4);
    unsigned short* W1t = (unsigned short*)w; w += align256((size_t)128 * 256 * 2);
    unsigned short* W2t = (unsigned short*)w; w += align256((size_t)256 * 256 * 2);
    unsigned short* W3t = (unsigned short*)w; w += align256((size_t)256 * 128 * 2);

    // CSR build
    hipMemsetAsync(gcnt, 0, (size_t)NG * 4, stream);
    k_bucket<<<N_EDGES / 4096, 256, 0, stream>>>(src, dst, gcnt, bucket);
    k_build<<<NG, 1024, 0, stream>>>(gcnt, bucket, rowptr, rowend, dinv, colp);

    // casts
    k_cast_scale<<<(N_NODES * 128 / 4) / 256, 256, 0, stream>>>(x, dinv, P0);
    k_wt_all<<<512, 256, 0, stream>>>(W1, W2, W3, W1t, W2t, W3t);

    // layer 1: fused agg(H=128) + gemm1 -> P2 (h1·dinv, H=256); 32 blocks/graph
    k_aggemm1<<<NG * 32, 256, 0, stream>>>(P0, rowptr, rowend, colp, dinv, W1t, b1, P2);

    // layers 2+3: fused agg(H=256) + gemm2+gemm3 -> P1 (h2@W3·dinv, H=128)
    k_aggemm23<<<NG * 32, 256, 0, stream>>>(P2, rowptr, rowend, colp, dinv, W2t, b2, W3t, P1);

    // layer 3 aggregation: agg(H=128) + b3 + tanh -> P0
    k_agg<128, true><<<N_NODES / 4, 256, 0, stream>>>(P1, P0, rowptr, rowend, colp, dinv, b3);

    // final FC
    k_fc<<<FC_SPLIT, 256, 0, stream>>>(P0, Wfc, fcpart);
    k_fc_reduce<<<NG * NOUT / 256, 256, 0, stream>>>(fcpart, bfc, out);
}

// Round 11
// 373.840 us; speedup vs baseline: 1.0260x; 1.0260x over previous
//
#include <hip/hip_runtime.h>
#include <math.h>

#define N_NODES 64000
#define N_EDGES 1048576
#define NB 1000
#define NG 64
#define NOUT 64
#define FC_SPLIT 500      // 500 x 256 = 128000 K-rows
#define BK_CAP 18000      // per-graph edge bucket capacity (mean 16384, +12.7 sigma)

typedef __attribute__((ext_vector_type(8))) short bfrag;   // 8 bf16 = 4 VGPRs
typedef __attribute__((ext_vector_type(4))) float f32x4;
typedef __attribute__((ext_vector_type(2))) float f32x2;

__device__ inline float bflo(unsigned int u) {
    union { unsigned int i; float f; } x; x.i = u << 16; return x.f;
}
__device__ inline float bfhi(unsigned int u) {
    union { unsigned int i; float f; } x; x.i = u & 0xffff0000u; return x.f;
}
__device__ inline f32x2 upk(unsigned int u) {   // {lo,hi} bf16 pair -> f32x2 (v_pk_add friendly)
    f32x2 r; r.x = bflo(u); r.y = bfhi(u); return r;
}
__device__ inline unsigned short f2bf(float f) {   // round-to-nearest-even
    union { float f; unsigned int i; } x; x.f = f;
    return (unsigned short)((x.i + 0x7FFFu + ((x.i >> 16) & 1u)) >> 16);
}
// fast tanh: 1 - 2/(e^{2x}+1). Saturates correctly; ~1e-6 abs error (<< bf16 quantization).
__device__ inline float tanh_fast(float x) {
    float e = __expf(2.0f * x);
    return fmaf(-2.0f, __builtin_amdgcn_rcpf(e + 1.0f), 1.0f);
}
// XOR swizzles: 16B-group g of row -> physical group. Involutions (swz(swz(g))=g).
__device__ inline int swz32(int row, int g) { return g ^ (row & 7) ^ (g >> 3); }  // 32 groups (256-short rows)
__device__ inline int swz16(int row, int g) { return g ^ (row & 7) ^ (g >> 3); }  // 16 groups (128-short rows)

// ---------------- CSR build, graph-bucketed ----------------

__global__ __launch_bounds__(256) void k_bucket(const int* __restrict__ src,
                                                const int* __restrict__ dst,
                                                int* __restrict__ gcnt,
                                                unsigned int* __restrict__ bucket) {
    __shared__ int lcnt[64];
    __shared__ int lbase[64];
    __shared__ int lcur[64];
    int t = threadIdx.x;
    int e0 = blockIdx.x * 4096;
    if (t < 64) { lcnt[t] = 0; lcur[t] = 0; }
    __syncthreads();
    for (int i = t; i < 4096; i += 256) {
        int d = dst[e0 + i];
        int g = d / NB;
        atomicAdd(&lcnt[g], 1);
    }
    __syncthreads();
    if (t < 64) lbase[t] = atomicAdd(&gcnt[t], lcnt[t]);
    __syncthreads();
    for (int i = t; i < 4096; i += 256) {
        int d = dst[e0 + i];
        int s = src[e0 + i];
        int g = d / NB;
        int pos = atomicAdd(&lcur[g], 1);
        unsigned int packed = ((unsigned int)(d - g * NB) << 10) | (unsigned int)(s - g * NB);
        bucket[(size_t)g * BK_CAP + lbase[g] + pos] = packed;
    }
}

__global__ __launch_bounds__(1024) void k_build(const int* __restrict__ gcnt,
                                                const unsigned int* __restrict__ bucket,
                                                int* __restrict__ rowptr,
                                                int* __restrict__ rowend,
                                                float* __restrict__ dinv,
                                                unsigned short* __restrict__ colp) {
    __shared__ int ind[1024];
    __shared__ int tmp[1024];
    int t = threadIdx.x;
    int g = blockIdx.x;
    int cnt = gcnt[g];
    size_t base = (size_t)g * BK_CAP;
    ind[t] = 0;
    __syncthreads();
    for (int i = t; i < cnt; i += 1024) {
        unsigned int p = bucket[base + i];
        atomicAdd(&ind[p >> 10], 1);
    }
    __syncthreads();
    int deg = ind[t];
    if (t < NB) dinv[g * NB + t] = rsqrtf((float)(deg + 1));
    tmp[t] = deg;
    __syncthreads();
    for (int off = 1; off < 1024; off <<= 1) {
        int o = (t >= off) ? tmp[t - off] : 0;
        __syncthreads();
        tmp[t] += o;
        __syncthreads();
    }
    int excl = tmp[t] - deg;
    if (t < NB) {
        rowptr[g * NB + t] = (int)base + excl;
        rowend[g * NB + t] = (int)base + excl + deg;
    }
    ind[t] = excl;           // reuse as cursor
    __syncthreads();
    for (int i = t; i < cnt; i += 1024) {
        unsigned int p = bucket[base + i];
        int dl = p >> 10;
        int pos = atomicAdd(&ind[dl], 1);
        colp[base + pos] = (unsigned short)(p & 1023u);
    }
}

// ---------------- casts ----------------

__global__ void k_cast_scale(const float* __restrict__ in, const float* __restrict__ dinv,
                             unsigned short* __restrict__ out) {
    int i = (blockIdx.x * blockDim.x + threadIdx.x) * 4;
    float d = dinv[i >> 7];
    float4 v = *(const float4*)(in + i);
    union { unsigned short s[4]; uint2 u; } o;
    o.s[0] = f2bf(v.x * d); o.s[1] = f2bf(v.y * d);
    o.s[2] = f2bf(v.z * d); o.s[3] = f2bf(v.w * d);
    *(uint2*)(out + i) = o.u;
}

// all three W[K][N] fp32 -> Wt[N][K] bf16 transposes in one launch (512 blocks)
__global__ void k_wt_all(const float* __restrict__ W1, const float* __restrict__ W2,
                         const float* __restrict__ W3, unsigned short* __restrict__ W1t,
                         unsigned short* __restrict__ W2t, unsigned short* __restrict__ W3t) {
    int i = blockIdx.x * 256 + threadIdx.x;
    if (i < 32768) {                     // W1: 128x256
        int n = i / 128, k = i % 128;
        W1t[i] = f2bf(W1[k * 256 + n]);
    } else if (i < 98304) {              // W2: 256x256
        int j = i - 32768;
        int n = j / 256, k = j % 256;
        W2t[j] = f2bf(W2[k * 256 + n]);
    } else {                             // W3: 256x128
        int j = i - 98304;
        int n = j / 256, k = j % 256;
        W3t[j] = f2bf(W3[k * 128 + n]);
    }
}

// ---------------- standalone pull aggregation (layer 3 only) ----------------
// R7-proven: graph->XCD pinned blocks, readlane-broadcast gathers, tiered batching.

template <int H, bool TANH>
__global__ __launch_bounds__(256) void k_agg(const unsigned short* __restrict__ hs,
                                             unsigned short* __restrict__ op,
                                             const int* __restrict__ rowptr,
                                             const int* __restrict__ rowend,
                                             const unsigned short* __restrict__ col,
                                             const float* __restrict__ dinv,
                                             const float* __restrict__ bias) {
    constexpr int VEC = H / 64;
    int lane = threadIdx.x & 63;
    int b = blockIdx.x;
    int c = b & 7;
    int j = b >> 3;
    int g = c + 8 * (j / 250);
    int chunk = j % 250;
    int v = g * NB + chunk * 4 + (threadIdx.x >> 6);
    const unsigned short* gb = hs + (size_t)g * NB * H;
    f32x2 a0, a1;
    a0 = f32x2{0.f, 0.f}; a1 = f32x2{0.f, 0.f};
    {
        const unsigned short* r = hs + (size_t)v * H + lane * VEC;
        if (VEC == 2) {
            a0 = upk(*(const unsigned int*)r);
        } else {
            uint2 u = *(const uint2*)r;
            a0 = upk(u.x); a1 = upk(u.y);
        }
    }
    int beg = rowptr[v], end = rowend[v];
    for (int e0 = beg; e0 < end; e0 += 64) {
        int me = e0 + lane;
        int s = (me < end) ? (int)col[me] : 0;
        int cnt = min(64, end - e0);
        int i = 0;
        for (; i + 8 <= cnt; i += 8) {
            int sx[8];
#pragma unroll
            for (int q = 0; q < 8; ++q) sx[q] = __builtin_amdgcn_readlane(s, i + q);
            if (VEC == 2) {
                unsigned int u[8];
#pragma unroll
                for (int q = 0; q < 8; ++q)
                    u[q] = *(const unsigned int*)(gb + (size_t)sx[q] * H + lane * 2);
#pragma unroll
                for (int q = 0; q < 8; ++q) a0 += upk(u[q]);
            } else {
                uint2 u[8];
#pragma unroll
                for (int q = 0; q < 8; ++q)
                    u[q] = *(const uint2*)(gb + (size_t)sx[q] * H + lane * 4);
#pragma unroll
                for (int q = 0; q < 8; ++q) { a0 += upk(u[q].x); a1 += upk(u[q].y); }
            }
        }
        for (; i + 4 <= cnt; i += 4) {
            int sx[4];
#pragma unroll
            for (int q = 0; q < 4; ++q) sx[q] = __builtin_amdgcn_readlane(s, i + q);
            if (VEC == 2) {
                unsigned int u[4];
#pragma unroll
                for (int q = 0; q < 4; ++q)
                    u[q] = *(const unsigned int*)(gb + (size_t)sx[q] * H + lane * 2);
#pragma unroll
                for (int q = 0; q < 4; ++q) a0 += upk(u[q]);
            } else {
                uint2 u[4];
#pragma unroll
                for (int q = 0; q < 4; ++q)
                    u[q] = *(const uint2*)(gb + (size_t)sx[q] * H + lane * 4);
#pragma unroll
                for (int q = 0; q < 4; ++q) { a0 += upk(u[q].x); a1 += upk(u[q].y); }
            }
        }
        for (; i < cnt; ++i) {
            int ss = __builtin_amdgcn_readlane(s, i);
            if (VEC == 2) {
                a0 += upk(*(const unsigned int*)(gb + (size_t)ss * H + lane * 2));
            } else {
                uint2 u = *(const uint2*)(gb + (size_t)ss * H + lane * 4);
                a0 += upk(u.x); a1 += upk(u.y);
            }
        }
    }
    float dv = dinv[v];
    float acc[4];
    acc[0] = a0.x; acc[1] = a0.y;
    if (VEC == 4) { acc[2] = a1.x; acc[3] = a1.y; }
    if (TANH) {
#pragma unroll
        for (int q = 0; q < VEC; ++q) acc[q] = tanh_fast(acc[q] * dv + bias[lane * VEC + q]);
    } else {
#pragma unroll
        for (int q = 0; q < VEC; ++q) acc[q] *= dv;
    }
    unsigned short* o = op + (size_t)v * H + lane * VEC;
    if (VEC == 2) {
        union { unsigned short s[2]; unsigned int u; } pk;
        pk.s[0] = f2bf(acc[0]); pk.s[1] = f2bf(acc[1]);
        *(unsigned int*)o = pk.u;
    } else {
        union { unsigned short s[4]; uint2 u; } pk;
        pk.s[0] = f2bf(acc[0]); pk.s[1] = f2bf(acc[1]);
        pk.s[2] = f2bf(acc[2]); pk.s[3] = f2bf(acc[3]);
        *(uint2*)o = pk.u;
    }
}

// ---- fused-kernel block mapping: 32 blocks/graph, graph->XCD pinned ----
// b = xcd + 8*j; g = xcd + 8*(j>>5); chunk = j&31. All blocks of graph g have
// b == g (mod 8) -> same XCD -> graph slice stays in one L2. chunk 31: 8 rows.
// __launch_bounds__(256,6): VGPR cap ~85 (kernel wants 56 -> NO spill; R10's
// (256,8) clamped to 32 VGPR and spilled ~100MB scratch traffic). LDS 6x16=96KB.

// ---------------- FUSED agg(H=128) + layer-1 GEMM ----------------

__global__ __launch_bounds__(256, 6) void k_aggemm1(const unsigned short* __restrict__ P0,
                                                    const int* __restrict__ rowptr,
                                                    const int* __restrict__ rowend,
                                                    const unsigned short* __restrict__ col,
                                                    const float* __restrict__ dinv,
                                                    const unsigned short* __restrict__ W1t,
                                                    const float* __restrict__ b1,
                                                    unsigned short* __restrict__ C) {
    constexpr int K = 128, N = 256;
    __shared__ unsigned short at[32 * 128];   // 8 KB, swizzled A-tile
    int t = threadIdx.x;
    int w = t >> 6, l = t & 63;
    int lm = l & 15, lq = l >> 4;
    int n0 = w * 64;
    int row0 = lq * 4;
    int b = blockIdx.x;
    int xcd = b & 7, jj = b >> 3;
    int g = xcd + 8 * (jj >> 5);
    int chunk = jj & 31;
    int m0 = g * NB + chunk * 32;             // first node of tile
    int nvalid = min(32, NB - chunk * 32);    // 8 for chunk==31
    const unsigned short* gb = P0 + (size_t)g * NB * K;

    // ---- phase 1: gather 8 rows per wave (wave-uniform validity) ----
    for (int r = 0; r < 8; ++r) {
        int row = w * 8 + r;
        unsigned int* slot = (unsigned int*)&at[row * 128 + swz16(row, l >> 2) * 8 + (l & 3) * 2];
        if (row < nvalid) {
            int v = m0 + row;
            f32x2 a0 = upk(*(const unsigned int*)(P0 + (size_t)v * K + l * 2));  // self
            int beg = rowptr[v], end = rowend[v];
            for (int e0 = beg; e0 < end; e0 += 64) {
                int me = e0 + l;
                int s = (me < end) ? (int)col[me] : 0;
                int cnt = min(64, end - e0);
                int i = 0;
                for (; i + 8 <= cnt; i += 8) {
                    int sx[8];
#pragma unroll
                    for (int q = 0; q < 8; ++q) sx[q] = __builtin_amdgcn_readlane(s, i + q);
                    unsigned int u[8];
#pragma unroll
                    for (int q = 0; q < 8; ++q)
                        u[q] = *(const unsigned int*)(gb + (size_t)sx[q] * K + l * 2);
#pragma unroll
                    for (int q = 0; q < 8; ++q) a0 += upk(u[q]);
                }
                for (; i + 4 <= cnt; i += 4) {
                    int sx[4];
#pragma unroll
                    for (int q = 0; q < 4; ++q) sx[q] = __builtin_amdgcn_readlane(s, i + q);
                    unsigned int u[4];
#pragma unroll
                    for (int q = 0; q < 4; ++q)
                        u[q] = *(const unsigned int*)(gb + (size_t)sx[q] * K + l * 2);
#pragma unroll
                    for (int q = 0; q < 4; ++q) a0 += upk(u[q]);
                }
                for (; i < cnt; ++i) {
                    int ss = __builtin_amdgcn_readlane(s, i);
                    a0 += upk(*(const unsigned int*)(gb + (size_t)ss * K + l * 2));
                }
            }
            float dv = dinv[v];
            union { unsigned short s2[2]; unsigned int u; } pk;
            pk.s2[0] = f2bf(a0.x * dv); pk.s2[1] = f2bf(a0.y * dv);
            *slot = pk.u;
        } else {
            *slot = 0u;
        }
    }
    __syncthreads();

    // ---- phase 2: C = tanh(A @ W1 + b1) * dinv, W1 streamed (double-buffered) ----
    f32x4 acc[2][4] = {};
    const unsigned short* Bb = W1t + (size_t)(n0 + lm) * K + lq * 8;
    bfrag bfb[2][4];
#pragma unroll
    for (int j = 0; j < 4; ++j) bfb[0][j] = *(const bfrag*)(Bb + (size_t)j * 16 * K);
#pragma unroll
    for (int it = 0; it < K / 32; ++it) {
        int ks = it * 32, cur = it & 1;
        if (it + 1 < K / 32) {
#pragma unroll
            for (int j = 0; j < 4; ++j)
                bfb[cur ^ 1][j] = *(const bfrag*)(Bb + (size_t)j * 16 * K + ks + 32);
        }
        bfrag af[2];
        int gidx = it * 4 + lq;
#pragma unroll
        for (int i = 0; i < 2; ++i) {
            int row = i * 16 + lm;
            af[i] = *(const bfrag*)&at[row * 128 + swz16(row, gidx) * 8];
        }
#pragma unroll
        for (int i = 0; i < 2; ++i)
#pragma unroll
            for (int j = 0; j < 4; ++j)
                acc[i][j] = __builtin_amdgcn_mfma_f32_16x16x32_bf16(af[i], bfb[cur][j], acc[i][j], 0, 0, 0);
    }
    float bj[4];
#pragma unroll
    for (int j = 0; j < 4; ++j) bj[j] = b1[n0 + j * 16 + lm];
#pragma unroll
    for (int i = 0; i < 2; ++i)
#pragma unroll
        for (int r = 0; r < 4; ++r) {
            int rr = i * 16 + row0 + r;
            if (rr < nvalid) {
                float dv = dinv[m0 + rr];
#pragma unroll
                for (int j = 0; j < 4; ++j) {
                    float v = tanh_fast(acc[i][j][r] + bj[j]) * dv;
                    C[(size_t)(m0 + rr) * N + n0 + j * 16 + lm] = f2bf(v);
                }
            }
        }
}

// ---------------- FUSED agg(H=256) + layers 2+3 GEMM ----------------

__global__ __launch_bounds__(256, 6) void k_aggemm23(const unsigned short* __restrict__ P2,
                                                     const int* __restrict__ rowptr,
                                                     const int* __restrict__ rowend,
                                                     const unsigned short* __restrict__ col,
                                                     const float* __restrict__ dinv,
                                                     const unsigned short* __restrict__ W2t,
                                                     const float* __restrict__ b2,
                                                     const unsigned short* __restrict__ W3t,
                                                     unsigned short* __restrict__ C) {
    constexpr int K = 256, N3 = 128;
    __shared__ unsigned short at[32 * 256];   // 16 KB, swizzled; A-tile then C2
    int t = threadIdx.x;
    int w = t >> 6, l = t & 63;
    int lm = l & 15, lq = l >> 4;
    int n0 = w * 64;
    int row0 = lq * 4;
    int b = blockIdx.x;
    int xcd = b & 7, jj = b >> 3;
    int g = xcd + 8 * (jj >> 5);
    int chunk = jj & 31;
    int m0 = g * NB + chunk * 32;
    int nvalid = min(32, NB - chunk * 32);
    const unsigned short* gb = P2 + (size_t)g * NB * K;

    // ---- phase 1: gather 8 rows per wave (uint2 per lane) ----
    for (int r = 0; r < 8; ++r) {
        int row = w * 8 + r;
        uint2* slot = (uint2*)&at[row * 256 + swz32(row, l >> 1) * 8 + (l & 1) * 4];
        if (row < nvalid) {
            int v = m0 + row;
            f32x2 a0, a1;
            {
                uint2 u = *(const uint2*)(P2 + (size_t)v * K + l * 4);   // self
                a0 = upk(u.x); a1 = upk(u.y);
            }
            int beg = rowptr[v], end = rowend[v];
            for (int e0 = beg; e0 < end; e0 += 64) {
                int me = e0 + l;
                int s = (me < end) ? (int)col[me] : 0;
                int cnt = min(64, end - e0);
                int i = 0;
                for (; i + 8 <= cnt; i += 8) {
                    int sx[8];
#pragma unroll
                    for (int q = 0; q < 8; ++q) sx[q] = __builtin_amdgcn_readlane(s, i + q);
                    uint2 u[8];
#pragma unroll
                    for (int q = 0; q < 8; ++q)
                        u[q] = *(const uint2*)(gb + (size_t)sx[q] * K + l * 4);
#pragma unroll
                    for (int q = 0; q < 8; ++q) { a0 += upk(u[q].x); a1 += upk(u[q].y); }
                }
                for (; i + 4 <= cnt; i += 4) {
                    int sx[4];
#pragma unroll
                    for (int q = 0; q < 4; ++q) sx[q] = __builtin_amdgcn_readlane(s, i + q);
                    uint2 u[4];
#pragma unroll
                    for (int q = 0; q < 4; ++q)
                        u[q] = *(const uint2*)(gb + (size_t)sx[q] * K + l * 4);
#pragma unroll
                    for (int q = 0; q < 4; ++q) { a0 += upk(u[q].x); a1 += upk(u[q].y); }
                }
                for (; i < cnt; ++i) {
                    int ss = __builtin_amdgcn_readlane(s, i);
                    uint2 u = *(const uint2*)(gb + (size_t)ss * K + l * 4);
                    a0 += upk(u.x); a1 += upk(u.y);
                }
            }
            float dv = dinv[v];
            union { unsigned short s4[4]; uint2 u; } pk;
            pk.s4[0] = f2bf(a0.x * dv); pk.s4[1] = f2bf(a0.y * dv);
            pk.s4[2] = f2bf(a1.x * dv); pk.s4[3] = f2bf(a1.y * dv);
            *slot = pk.u;
        } else {
            uint2 z; z.x = 0u; z.y = 0u;
            *slot = z;
        }
    }
    __syncthreads();

    // ---- stage 1: C2 = tanh(A @ W2 + b2), W2 streamed (double-buffered) ----
    f32x4 acc[2][4] = {};
    {
        const unsigned short* Bb = W2t + (size_t)(n0 + lm) * K + lq * 8;
        bfrag bfb[2][4];
#pragma unroll
        for (int j = 0; j < 4; ++j) bfb[0][j] = *(const bfrag*)(Bb + (size_t)j * 16 * K);
#pragma unroll
        for (int it = 0; it < K / 32; ++it) {
            int ks = it * 32, cur = it & 1;
            if (it + 1 < K / 32) {
#pragma unroll
                for (int j = 0; j < 4; ++j)
                    bfb[cur ^ 1][j] = *(const bfrag*)(Bb + (size_t)j * 16 * K + ks + 32);
            }
            bfrag af[2];
            int gidx = it * 4 + lq;
#pragma unroll
            for (int i = 0; i < 2; ++i) {
                int row = i * 16 + lm;
                af[i] = *(const bfrag*)&at[row * 256 + swz32(row, gidx) * 8];
            }
#pragma unroll
            for (int i = 0; i < 2; ++i)
#pragma unroll
                for (int j = 0; j < 4; ++j)
                    acc[i][j] = __builtin_amdgcn_mfma_f32_16x16x32_bf16(af[i], bfb[cur][j], acc[i][j], 0, 0, 0);
        }
    }
    __syncthreads();   // all stage-1 A-reads done; safe to overwrite with C2
    {
        float bj[4];
#pragma unroll
        for (int j = 0; j < 4; ++j) bj[j] = b2[n0 + j * 16 + lm];
#pragma unroll
        for (int i = 0; i < 2; ++i)
#pragma unroll
            for (int j = 0; j < 4; ++j) {
                int colb = n0 + j * 16 + lm;
                int gidx = colb >> 3, off = colb & 7;
#pragma unroll
                for (int r = 0; r < 4; ++r) {
                    int row = i * 16 + row0 + r;
                    at[row * 256 + swz32(row, gidx) * 8 + off] =
                        f2bf(tanh_fast(acc[i][j][r] + bj[j]));
                }
            }
    }
    __syncthreads();
    // ---- stage 2: C3 = (C2 @ W3) * dinv, W3 streamed (prefetch-1) ----
    {
        f32x4 acc2[2][2] = {};
        int n3 = w * 32;
        const unsigned short* Bb = W3t + (size_t)(n3 + lm) * K + lq * 8;
        bfrag bfb[2][2];
#pragma unroll
        for (int j = 0; j < 2; ++j) bfb[0][j] = *(const bfrag*)(Bb + (size_t)j * 16 * K);
#pragma unroll
        for (int it = 0; it < K / 32; ++it) {
            int ks = it * 32, cur = it & 1;
            if (it + 1 < K / 32) {
#pragma unroll
                for (int j = 0; j < 2; ++j)
                    bfb[cur ^ 1][j] = *(const bfrag*)(Bb + (size_t)j * 16 * K + ks + 32);
            }
            bfrag af[2];
            int gidx = it * 4 + lq;
#pragma unroll
            for (int i = 0; i < 2; ++i) {
                int row = i * 16 + lm;
                af[i] = *(const bfrag*)&at[row * 256 + swz32(row, gidx) * 8];
            }
#pragma unroll
            for (int i = 0; i < 2; ++i)
#pragma unroll
                for (int j = 0; j < 2; ++j)
                    acc2[i][j] = __builtin_amdgcn_mfma_f32_16x16x32_bf16(af[i], bfb[cur][j], acc2[i][j], 0, 0, 0);
        }
        int n3b = w * 32;
#pragma unroll
        for (int i = 0; i < 2; ++i)
#pragma unroll
            for (int r = 0; r < 4; ++r) {
                int rr = i * 16 + row0 + r;
                if (rr < nvalid) {
                    float dv = dinv[m0 + rr];
#pragma unroll
                    for (int j = 0; j < 2; ++j)
                        C[(size_t)(m0 + rr) * N3 + n3b + j * 16 + lm] =
                            f2bf(acc2[i][j][r] * dv);
                }
            }
    }
}

// ---------------- final FC: out[64,64] = h[64,128000](bf16) @ Wfc[128000,64](f32) + bfc

__global__ void k_fc(const unsigned short* __restrict__ A, const float* __restrict__ B,
                     float* __restrict__ part) {
    __shared__ float As[16][68];
    __shared__ float Bs[16][68];
    const int KROW = NB * 128;         // 128000
    int t = threadIdx.x;
    int tx = t & 15, ty = t >> 4;
    int k0b = blockIdx.x * 256;
    float acc[4][4] = {};
    for (int k0 = k0b; k0 < k0b + 256; k0 += 16) {
        int arow = t >> 2, ak = (t & 3) << 2;
        uint2 ua = *(const uint2*)(A + (size_t)arow * KROW + k0 + ak);
        As[ak + 0][arow] = bflo(ua.x);
        As[ak + 1][arow] = bfhi(ua.x);
        As[ak + 2][arow] = bflo(ua.y);
        As[ak + 3][arow] = bfhi(ua.y);
        int bk = t >> 4, bn4 = (t & 15) << 2;
        *(float4*)&Bs[bk][bn4] = *(const float4*)(B + (size_t)(k0 + bk) * NOUT + bn4);
        __syncthreads();
#pragma unroll
        for (int kk = 0; kk < 16; ++kk) {
            float4 a = *(const float4*)&As[kk][ty << 2];
            float4 b = *(const float4*)&Bs[kk][tx << 2];
            acc[0][0] += a.x * b.x; acc[0][1] += a.x * b.y; acc[0][2] += a.x * b.z; acc[0][3] += a.x * b.w;
            acc[1][0] += a.y * b.x; acc[1][1] += a.y * b.y; acc[1][2] += a.y * b.z; acc[1][3] += a.y * b.w;
            acc[2][0] += a.z * b.x; acc[2][1] += a.z * b.y; acc[2][2] += a.z * b.z; acc[2][3] += a.z * b.w;
            acc[3][0] += a.w * b.x; acc[3][1] += a.w * b.y; acc[3][2] += a.w * b.z; acc[3][3] += a.w * b.w;
        }
        __syncthreads();
    }
    float* po = part + (size_t)blockIdx.x * (NG * NOUT);
#pragma unroll
    for (int i = 0; i < 4; ++i) {
        float4 r;
        r.x = acc[i][0]; r.y = acc[i][1]; r.z = acc[i][2]; r.w = acc[i][3];
        *(float4*)&po[((ty << 2) + i) * NOUT + (tx << 2)] = r;
    }
}

__global__ void k_fc_reduce(const float* __restrict__ part, const float* __restrict__ bfc,
                            float* __restrict__ out) {
    int i = blockIdx.x * blockDim.x + threadIdx.x;   // 4096 threads
    float s = bfc[i & 63];
    for (int b = 0; b < FC_SPLIT; ++b) s += part[(size_t)b * (NG * NOUT) + i];
    out[i] = s;
}

// ---------------- driver ----------------

static inline size_t align256(size_t x) { return (x + 255) & ~(size_t)255; }

extern "C" void kernel_launch(void* const* d_in, const int* in_sizes, int n_in,
                              void* d_out, int out_size, void* d_ws, size_t ws_size,
                              hipStream_t stream) {
    const float* x   = (const float*)d_in[0];
    const int*   ei  = (const int*)d_in[1];
    const int*   src = ei;
    const int*   dst = ei + N_EDGES;
    const float* W1  = (const float*)d_in[3];
    const float* b1  = (const float*)d_in[4];
    const float* W2  = (const float*)d_in[5];
    const float* b2  = (const float*)d_in[6];
    const float* W3  = (const float*)d_in[7];
    const float* b3  = (const float*)d_in[8];
    const float* Wfc = (const float*)d_in[9];
    const float* bfc = (const float*)d_in[10];
    float* out = (float*)d_out;

    char* w = (char*)d_ws;
    unsigned short* P0 = (unsigned short*)w; w += align256((size_t)N_NODES * 256 * 2);
    unsigned short* P1 = (unsigned short*)w; w += align256((size_t)N_NODES * 256 * 2);
    unsigned short* P2 = (unsigned short*)w; w += align256((size_t)N_NODES * 256 * 2);
    int* rowptr = (int*)w;      w += align256((size_t)N_NODES * 4);
    int* rowend = (int*)w;      w += align256((size_t)N_NODES * 4);
    float* dinv = (float*)w;    w += align256((size_t)N_NODES * 4);
    int* gcnt = (int*)w;        w += align256((size_t)NG * 4);
    unsigned int* bucket = (unsigned int*)w; w += align256((size_t)NG * BK_CAP * 4);
    unsigned short* colp = (unsigned short*)w; w += align256((size_t)NG * BK_CAP * 2);
    float* fcpart = (float*)w;  w += align256((size_t)FC_SPLIT * NG * NOUT * 4);
    unsigned short* W1t = (unsigned short*)w; w += align256((size_t)128 * 256 * 2);
    unsigned short* W2t = (unsigned short*)w; w += align256((size_t)256 * 256 * 2);
    unsigned short* W3t = (unsigned short*)w; w += align256((size_t)256 * 128 * 2);

    // CSR build
    hipMemsetAsync(gcnt, 0, (size_t)NG * 4, stream);
    k_bucket<<<N_EDGES / 4096, 256, 0, stream>>>(src, dst, gcnt, bucket);
    k_build<<<NG, 1024, 0, stream>>>(gcnt, bucket, rowptr, rowend, dinv, colp);

    // casts
    k_cast_scale<<<(N_NODES * 128 / 4) / 256, 256, 0, stream>>>(x, dinv, P0);
    k_wt_all<<<512, 256, 0, stream>>>(W1, W2, W3, W1t, W2t, W3t);

    // layer 1: fused agg(H=128) + gemm1 -> P2 (h1·dinv, H=256); 32 blocks/graph
    k_aggemm1<<<NG * 32, 256, 0, stream>>>(P0, rowptr, rowend, colp, dinv, W1t, b1, P2);

    // layers 2+3: fused agg(H=256) + gemm2+gemm3 -> P1 (h2@W3·dinv, H=128)
    k_aggemm23<<<NG * 32, 256, 0, stream>>>(P2, rowptr, rowend, colp, dinv, W2t, b2, W3t, P1);

    // layer 3 aggregation: agg(H=128) + b3 + tanh -> P0
    k_agg<128, true><<<N_NODES / 4, 256, 0, stream>>>(P1, P0, rowptr, rowend, colp, dinv, b3);

    // final FC
    k_fc<<<FC_SPLIT, 256, 0, stream>>>(P0, Wfc, fcpart);
    k_fc_reduce<<<NG * NOUT / 256, 256, 0, stream>>>(fcpart, bfc, out);
}

// Round 12
// 330.828 us; speedup vs baseline: 1.1594x; 1.1300x over previous
//
#include <hip/hip_runtime.h>
#include <math.h>

#define N_NODES 64000
#define N_EDGES 1048576
#define NB 1000
#define NG 64
#define NOUT 64
#define FC_SPLIT 500      // 500 x 256 = 128000 K-rows
#define BK_CAP 18000      // per-graph edge bucket capacity (mean 16384, +12.7 sigma)

typedef __attribute__((ext_vector_type(8))) short bfrag;   // 8 bf16 = 4 VGPRs
typedef __attribute__((ext_vector_type(4))) float f32x4;
typedef __attribute__((ext_vector_type(2))) float f32x2;

__device__ inline float bflo(unsigned int u) {
    union { unsigned int i; float f; } x; x.i = u << 16; return x.f;
}
__device__ inline float bfhi(unsigned int u) {
    union { unsigned int i; float f; } x; x.i = u & 0xffff0000u; return x.f;
}
__device__ inline f32x2 upk(unsigned int u) {   // {lo,hi} bf16 pair -> f32x2 (v_pk_add friendly)
    f32x2 r; r.x = bflo(u); r.y = bfhi(u); return r;
}
__device__ inline unsigned short f2bf(float f) {   // round-to-nearest-even
    union { float f; unsigned int i; } x; x.f = f;
    return (unsigned short)((x.i + 0x7FFFu + ((x.i >> 16) & 1u)) >> 16);
}
// fast tanh: 1 - 2/(e^{2x}+1). Saturates correctly; ~1e-6 abs error (<< bf16 quantization).
__device__ inline float tanh_fast(float x) {
    float e = __expf(2.0f * x);
    return fmaf(-2.0f, __builtin_amdgcn_rcpf(e + 1.0f), 1.0f);
}
// XOR swizzles: 16B-group g of row -> physical group. Involutions (swz(swz(g))=g).
__device__ inline int swz32(int row, int g) { return g ^ (row & 7) ^ (g >> 3); }  // 32 groups (256-short rows)
__device__ inline int swz16(int row, int g) { return g ^ (row & 7) ^ (g >> 3); }  // 16 groups (128-short rows)

// async global->LDS, 16B per lane. LDS dest must be wave-uniform; lane l writes dest + l*16B.
__device__ inline void gload_lds16(const unsigned short* g, unsigned short* l) {
    __builtin_amdgcn_global_load_lds(
        (const __attribute__((address_space(1))) void*)g,
        (__attribute__((address_space(3))) void*)l, 16, 0, 0);
}

// ---------------- CSR build, graph-bucketed ----------------

__global__ __launch_bounds__(256) void k_bucket(const int* __restrict__ src,
                                                const int* __restrict__ dst,
                                                int* __restrict__ gcnt,
                                                unsigned int* __restrict__ bucket) {
    __shared__ int lcnt[64];
    __shared__ int lbase[64];
    __shared__ int lcur[64];
    int t = threadIdx.x;
    int e0 = blockIdx.x * 4096;
    if (t < 64) { lcnt[t] = 0; lcur[t] = 0; }
    __syncthreads();
    for (int i = t; i < 4096; i += 256) {
        int d = dst[e0 + i];
        int g = d / NB;
        atomicAdd(&lcnt[g], 1);
    }
    __syncthreads();
    if (t < 64) lbase[t] = atomicAdd(&gcnt[t], lcnt[t]);
    __syncthreads();
    for (int i = t; i < 4096; i += 256) {
        int d = dst[e0 + i];
        int s = src[e0 + i];
        int g = d / NB;
        int pos = atomicAdd(&lcur[g], 1);
        unsigned int packed = ((unsigned int)(d - g * NB) << 10) | (unsigned int)(s - g * NB);
        bucket[(size_t)g * BK_CAP + lbase[g] + pos] = packed;
    }
}

__global__ __launch_bounds__(1024) void k_build(const int* __restrict__ gcnt,
                                                const unsigned int* __restrict__ bucket,
                                                int* __restrict__ rowptr,
                                                int* __restrict__ rowend,
                                                float* __restrict__ dinv,
                                                unsigned short* __restrict__ colp) {
    __shared__ int ind[1024];
    __shared__ int tmp[1024];
    int t = threadIdx.x;
    int g = blockIdx.x;
    int cnt = gcnt[g];
    size_t base = (size_t)g * BK_CAP;
    ind[t] = 0;
    __syncthreads();
    for (int i = t; i < cnt; i += 1024) {
        unsigned int p = bucket[base + i];
        atomicAdd(&ind[p >> 10], 1);
    }
    __syncthreads();
    int deg = ind[t];
    if (t < NB) dinv[g * NB + t] = rsqrtf((float)(deg + 1));
    tmp[t] = deg;
    __syncthreads();
    for (int off = 1; off < 1024; off <<= 1) {
        int o = (t >= off) ? tmp[t - off] : 0;
        __syncthreads();
        tmp[t] += o;
        __syncthreads();
    }
    int excl = tmp[t] - deg;
    if (t < NB) {
        rowptr[g * NB + t] = (int)base + excl;
        rowend[g * NB + t] = (int)base + excl + deg;
    }
    ind[t] = excl;           // reuse as cursor
    __syncthreads();
    for (int i = t; i < cnt; i += 1024) {
        unsigned int p = bucket[base + i];
        int dl = p >> 10;
        int pos = atomicAdd(&ind[dl], 1);
        colp[base + pos] = (unsigned short)(p & 1023u);
    }
}

// ---------------- prep: input cast+prescale AND the 3 weight transposes, one launch ----
// blocks [0,8000): P0 = bf16(x * dinv-row); blocks [8000,8512): W1t/W2t/W3t.

__global__ void k_prep(const float* __restrict__ in, const float* __restrict__ dinv,
                       unsigned short* __restrict__ out,
                       const float* __restrict__ W1, const float* __restrict__ W2,
                       const float* __restrict__ W3, unsigned short* __restrict__ W1t,
                       unsigned short* __restrict__ W2t, unsigned short* __restrict__ W3t) {
    int b = blockIdx.x;
    if (b < 8000) {
        int i = (b * 256 + threadIdx.x) * 4;
        float d = dinv[i >> 7];
        float4 v = *(const float4*)(in + i);
        union { unsigned short s[4]; uint2 u; } o;
        o.s[0] = f2bf(v.x * d); o.s[1] = f2bf(v.y * d);
        o.s[2] = f2bf(v.z * d); o.s[3] = f2bf(v.w * d);
        *(uint2*)(out + i) = o.u;
    } else {
        int i = (b - 8000) * 256 + threadIdx.x;
        if (i < 32768) {                     // W1: 128x256
            int n = i / 128, k = i % 128;
            W1t[i] = f2bf(W1[k * 256 + n]);
        } else if (i < 98304) {              // W2: 256x256
            int j = i - 32768;
            int n = j / 256, k = j % 256;
            W2t[j] = f2bf(W2[k * 256 + n]);
        } else if (i < 131072) {             // W3: 256x128
            int j = i - 98304;
            int n = j / 256, k = j % 256;
            W3t[j] = f2bf(W3[k * 128 + n]);
        }
    }
}

// ---------------- pull aggregation (bf16 in / bf16 out, fp32 math) ----------------
// R7-proven: graph->XCD pinned blocks, readlane-broadcast gathers, tiered batching
// with tier-16 (two independent 8-batches in flight).

template <int H, bool TANH>
__global__ __launch_bounds__(256) void k_agg(const unsigned short* __restrict__ hs,
                                             unsigned short* __restrict__ op,
                                             const int* __restrict__ rowptr,
                                             const int* __restrict__ rowend,
                                             const unsigned short* __restrict__ col,
                                             const float* __restrict__ dinv,
                                             const float* __restrict__ bias) {
    constexpr int VEC = H / 64;
    int lane = threadIdx.x & 63;
    int b = blockIdx.x;
    int c = b & 7;
    int j = b >> 3;
    int g = c + 8 * (j / 250);
    int chunk = j % 250;
    int v = g * NB + chunk * 4 + (threadIdx.x >> 6);
    const unsigned short* gb = hs + (size_t)g * NB * H;
    f32x2 a0, a1, b0, b1v;
    a0 = f32x2{0.f, 0.f}; a1 = f32x2{0.f, 0.f};
    b0 = f32x2{0.f, 0.f}; b1v = f32x2{0.f, 0.f};
    {
        const unsigned short* r = hs + (size_t)v * H + lane * VEC;
        if (VEC == 2) {
            a0 = upk(*(const unsigned int*)r);
        } else {
            uint2 u = *(const uint2*)r;
            a0 = upk(u.x); a1 = upk(u.y);
        }
    }
    int beg = rowptr[v], end = rowend[v];
    for (int e0 = beg; e0 < end; e0 += 64) {
        int me = e0 + lane;
        int s = (me < end) ? (int)col[me] : 0;
        int cnt = min(64, end - e0);
        int i = 0;
        // ---- tier 16: two independent 8-batches, 16 loads in flight ----
        for (; i + 16 <= cnt; i += 16) {
            int sx[16];
#pragma unroll
            for (int q = 0; q < 16; ++q) sx[q] = __builtin_amdgcn_readlane(s, i + q);
            if (VEC == 2) {
                unsigned int uA[8], uB[8];
#pragma unroll
                for (int q = 0; q < 8; ++q)
                    uA[q] = *(const unsigned int*)(gb + (size_t)sx[q] * H + lane * 2);
#pragma unroll
                for (int q = 0; q < 8; ++q)
                    uB[q] = *(const unsigned int*)(gb + (size_t)sx[8 + q] * H + lane * 2);
#pragma unroll
                for (int q = 0; q < 8; ++q) a0 += upk(uA[q]);
#pragma unroll
                for (int q = 0; q < 8; ++q) b0 += upk(uB[q]);
            } else {
                uint2 uA[8], uB[8];
#pragma unroll
                for (int q = 0; q < 8; ++q)
                    uA[q] = *(const uint2*)(gb + (size_t)sx[q] * H + lane * 4);
#pragma unroll
                for (int q = 0; q < 8; ++q)
                    uB[q] = *(const uint2*)(gb + (size_t)sx[8 + q] * H + lane * 4);
#pragma unroll
                for (int q = 0; q < 8; ++q) { a0 += upk(uA[q].x); a1 += upk(uA[q].y); }
#pragma unroll
                for (int q = 0; q < 8; ++q) { b0 += upk(uB[q].x); b1v += upk(uB[q].y); }
            }
        }
        // ---- tier 8 ----
        for (; i + 8 <= cnt; i += 8) {
            int sx[8];
#pragma unroll
            for (int q = 0; q < 8; ++q) sx[q] = __builtin_amdgcn_readlane(s, i + q);
            if (VEC == 2) {
                unsigned int u[8];
#pragma unroll
                for (int q = 0; q < 8; ++q)
                    u[q] = *(const unsigned int*)(gb + (size_t)sx[q] * H + lane * 2);
#pragma unroll
                for (int q = 0; q < 8; ++q) a0 += upk(u[q]);
            } else {
                uint2 u[8];
#pragma unroll
                for (int q = 0; q < 8; ++q)
                    u[q] = *(const uint2*)(gb + (size_t)sx[q] * H + lane * 4);
#pragma unroll
                for (int q = 0; q < 8; ++q) { a0 += upk(u[q].x); a1 += upk(u[q].y); }
            }
        }
        // ---- tier 4 ----
        for (; i + 4 <= cnt; i += 4) {
            int sx[4];
#pragma unroll
            for (int q = 0; q < 4; ++q) sx[q] = __builtin_amdgcn_readlane(s, i + q);
            if (VEC == 2) {
                unsigned int u[4];
#pragma unroll
                for (int q = 0; q < 4; ++q)
                    u[q] = *(const unsigned int*)(gb + (size_t)sx[q] * H + lane * 2);
#pragma unroll
                for (int q = 0; q < 4; ++q) a0 += upk(u[q]);
            } else {
                uint2 u[4];
#pragma unroll
                for (int q = 0; q < 4; ++q)
                    u[q] = *(const uint2*)(gb + (size_t)sx[q] * H + lane * 4);
#pragma unroll
                for (int q = 0; q < 4; ++q) { a0 += upk(u[q].x); a1 += upk(u[q].y); }
            }
        }
        // ---- tier 1 ----
        for (; i < cnt; ++i) {
            int ss = __builtin_amdgcn_readlane(s, i);
            if (VEC == 2) {
                a0 += upk(*(const unsigned int*)(gb + (size_t)ss * H + lane * 2));
            } else {
                uint2 u = *(const uint2*)(gb + (size_t)ss * H + lane * 4);
                a0 += upk(u.x); a1 += upk(u.y);
            }
        }
    }
    a0 += b0; a1 += b1v;
    float dv = dinv[v];
    float acc[4];
    acc[0] = a0.x; acc[1] = a0.y;
    if (VEC == 4) { acc[2] = a1.x; acc[3] = a1.y; }
    if (TANH) {
#pragma unroll
        for (int q = 0; q < VEC; ++q) acc[q] = tanh_fast(acc[q] * dv + bias[lane * VEC + q]);
    } else {
#pragma unroll
        for (int q = 0; q < VEC; ++q) acc[q] *= dv;
    }
    unsigned short* o = op + (size_t)v * H + lane * VEC;
    if (VEC == 2) {
        union { unsigned short s[2]; unsigned int u; } pk;
        pk.s[0] = f2bf(acc[0]); pk.s[1] = f2bf(acc[1]);
        *(unsigned int*)o = pk.u;
    } else {
        union { unsigned short s[4]; uint2 u; } pk;
        pk.s[0] = f2bf(acc[0]); pk.s[1] = f2bf(acc[1]);
        pk.s[2] = f2bf(acc[2]); pk.s[3] = f2bf(acc[3]);
        *(uint2*)o = pk.u;
    }
}

// ---------------- layer-1 GEMM: C[64000,256] = tanh(A[64000,128] @ W1 + b1) * dinv
// M=64/block, grid 1000 (4000 waves). W1-slice resident in registers (64 VGPR).
// Single barrier in the whole kernel; inner loop pure LDS+MFMA. (P3/R7-proven.)

__global__ __launch_bounds__(256, 2) void k_gemm1(const unsigned short* __restrict__ A,
                                                  const unsigned short* __restrict__ W1t,
                                                  const float* __restrict__ b1,
                                                  const float* __restrict__ dinv,
                                                  unsigned short* __restrict__ C) {
    constexpr int K = 128, N = 256;
    __shared__ unsigned short at[64 * 128];   // 16 KB, XOR-swizzled
    int t = threadIdx.x;
    int w = t >> 6, l = t & 63;
    int lm = l & 15, lq = l >> 4;
    int n0 = w * 64;
    int row0 = lq * 4;
    int m0 = blockIdx.x * 64;

    // stage A-tile: wave w rows w*16..w*16+15, 4 issues x 4 rows, pre-swizzled source
    {
        const unsigned short* Ab = A + (size_t)m0 * K;
#pragma unroll
        for (int q = 0; q < 4; ++q) {
            int rbase = w * 16 + q * 4;
            int row = rbase + (l >> 4);
            int g = swz16(row, l & 15);
            gload_lds16(Ab + (size_t)row * K + g * 8, &at[rbase * K]);
        }
    }
    // resident B1 (L2-hot after first blocks)
    bfrag B1[16];
    {
        const unsigned short* Bb = W1t + (size_t)(n0 + lm) * K + lq * 8;
#pragma unroll
        for (int j = 0; j < 4; ++j)
#pragma unroll
            for (int it = 0; it < 4; ++it)
                B1[j * 4 + it] = *(const bfrag*)(Bb + (size_t)j * 16 * K + it * 32);
    }
    float bj[4];
#pragma unroll
    for (int j = 0; j < 4; ++j) bj[j] = b1[n0 + j * 16 + lm];

    asm volatile("s_waitcnt vmcnt(0)\n\ts_barrier" ::: "memory");

    f32x4 acc[4][4] = {};
#pragma unroll
    for (int it = 0; it < 4; ++it) {
        bfrag af[4];
        int gidx = it * 4 + lq;
#pragma unroll
        for (int i = 0; i < 4; ++i) {
            int row = i * 16 + lm;
            af[i] = *(const bfrag*)&at[row * K + swz16(row, gidx) * 8];
        }
#pragma unroll
        for (int i = 0; i < 4; ++i)
#pragma unroll
            for (int j = 0; j < 4; ++j)
                acc[i][j] = __builtin_amdgcn_mfma_f32_16x16x32_bf16(af[i], B1[j * 4 + it], acc[i][j], 0, 0, 0);
    }
    float drow[4][4];
#pragma unroll
    for (int i = 0; i < 4; ++i)
#pragma unroll
        for (int r = 0; r < 4; ++r) drow[i][r] = dinv[m0 + i * 16 + row0 + r];
#pragma unroll
    for (int i = 0; i < 4; ++i)
#pragma unroll
        for (int j = 0; j < 4; ++j)
#pragma unroll
            for (int r = 0; r < 4; ++r) {
                float v = tanh_fast(acc[i][j][r] + bj[j]) * drow[i][r];
                C[(size_t)(m0 + i * 16 + row0 + r) * N + n0 + j * 16 + lm] = f2bf(v);
            }
}

// ---------------- fused layers 2+3 GEMM (P3/R7-proven form):
// M=64/block, grid 1000. W2-slice resident (128 VGPR); W3-slice preloaded during
// stage-1 (depth-2 + rolling prefetch). stage1 C2 = tanh(A@W2+b2) written back
// into the same 32KB LDS buffer; stage2 C3 = (C2@W3)*dinv.

__global__ __launch_bounds__(256, 2) void k_gemm23(const unsigned short* __restrict__ A,
                                                   const unsigned short* __restrict__ W2t,
                                                   const float* __restrict__ b2,
                                                   const unsigned short* __restrict__ W3t,
                                                   const float* __restrict__ dinv,
                                                   unsigned short* __restrict__ C) {
    constexpr int K = 256, N3 = 128;
    __shared__ unsigned short at[64 * 256];   // 32 KB, XOR-swizzled; A-tile then C2
    int t = threadIdx.x;
    int w = t >> 6, l = t & 63;
    int lm = l & 15, lq = l >> 4;
    int n0 = w * 64;
    int row0 = lq * 4;
    int m0 = blockIdx.x * 64;
    int n3 = w * 32;
    const unsigned short* B3b = W3t + (size_t)(n3 + lm) * K + lq * 8;

    // stage A-tile: wave w rows w*16..w*16+15, 8 issues x 2 rows, pre-swizzled source
    {
        const unsigned short* Ab = A + (size_t)m0 * K;
#pragma unroll
        for (int q = 0; q < 8; ++q) {
            int rbase = w * 16 + q * 2;
            int row = rbase + (l >> 5);
            int g = swz32(row, l & 31);
            gload_lds16(Ab + (size_t)row * K + g * 8, &at[rbase * K]);
        }
    }
    // resident stage-1 B (full W2 column-slice of this wave)
    bfrag B1[32];
    {
        const unsigned short* Bb = W2t + (size_t)(n0 + lm) * K + lq * 8;
#pragma unroll
        for (int j = 0; j < 4; ++j)
#pragma unroll
            for (int it = 0; it < 8; ++it)
                B1[j * 8 + it] = *(const bfrag*)(Bb + (size_t)j * 16 * K + it * 32);
    }
    // stage-2 B rolling buffer: preload its 0,1 now (latency hidden under stage 1)
    bfrag bfb[4][2];
#pragma unroll
    for (int p = 0; p < 2; ++p)
#pragma unroll
        for (int j = 0; j < 2; ++j)
            bfb[p][j] = *(const bfrag*)(B3b + (size_t)j * 16 * K + p * 32);
    float bj[4];
#pragma unroll
    for (int j = 0; j < 4; ++j) bj[j] = b2[n0 + j * 16 + lm];

    asm volatile("s_waitcnt vmcnt(0)\n\ts_barrier" ::: "memory");

    // ---- stage 1: C2 = tanh(A @ W2 + b2), B from registers ----
    f32x4 acc[4][4] = {};
#pragma unroll
    for (int it = 0; it < 8; ++it) {
        bfrag af[4];
        int gidx = it * 4 + lq;
#pragma unroll
        for (int i = 0; i < 4; ++i) {
            int row = i * 16 + lm;
            af[i] = *(const bfrag*)&at[row * 256 + swz32(row, gidx) * 8];
        }
#pragma unroll
        for (int i = 0; i < 4; ++i)
#pragma unroll
            for (int j = 0; j < 4; ++j)
                acc[i][j] = __builtin_amdgcn_mfma_f32_16x16x32_bf16(af[i], B1[j * 8 + it], acc[i][j], 0, 0, 0);
    }
    asm volatile("s_waitcnt lgkmcnt(0)\n\ts_barrier" ::: "memory");   // A-reads done
    // ---- C2 writeback (tanh) into same buffer ----
#pragma unroll
    for (int i = 0; i < 4; ++i)
#pragma unroll
        for (int j = 0; j < 4; ++j) {
            int colb = n0 + j * 16 + lm;
            int gidx = colb >> 3, off = colb & 7;
#pragma unroll
            for (int r = 0; r < 4; ++r) {
                int row = i * 16 + row0 + r;
                at[row * 256 + swz32(row, gidx) * 8 + off] =
                    f2bf(tanh_fast(acc[i][j][r] + bj[j]));
            }
        }
    asm volatile("s_waitcnt lgkmcnt(0)\n\ts_barrier" ::: "memory");   // C2 visible
    // ---- stage 2: C3 = (C2 @ W3) * dinv, B preloaded/rolling (no exposed latency) ----
    {
        f32x4 acc2[4][2] = {};
#pragma unroll
        for (int it = 0; it < 8; ++it) {
            if (it + 2 < 8) {   // rolling prefetch, 2 ahead; slot index static after unroll
#pragma unroll
                for (int j = 0; j < 2; ++j)
                    bfb[(it + 2) & 3][j] = *(const bfrag*)(B3b + (size_t)j * 16 * K + (it + 2) * 32);
            }
            bfrag af[4];
            int gidx = it * 4 + lq;
#pragma unroll
            for (int i = 0; i < 4; ++i) {
                int row = i * 16 + lm;
                af[i] = *(const bfrag*)&at[row * 256 + swz32(row, gidx) * 8];
            }
#pragma unroll
            for (int i = 0; i < 4; ++i)
#pragma unroll
                for (int j = 0; j < 2; ++j)
                    acc2[i][j] = __builtin_amdgcn_mfma_f32_16x16x32_bf16(af[i], bfb[it & 3][j], acc2[i][j], 0, 0, 0);
        }
        float drow[4][4];
#pragma unroll
        for (int i = 0; i < 4; ++i)
#pragma unroll
            for (int r = 0; r < 4; ++r) drow[i][r] = dinv[m0 + i * 16 + row0 + r];
#pragma unroll
        for (int i = 0; i < 4; ++i)
#pragma unroll
            for (int j = 0; j < 2; ++j)
#pragma unroll
                for (int r = 0; r < 4; ++r)
                    C[(size_t)(m0 + i * 16 + row0 + r) * N3 + n3 + j * 16 + lm] =
                        f2bf(acc2[i][j][r] * drow[i][r]);
    }
}

// ---------------- final FC: out[64,64] = h[64,128000](bf16) @ Wfc[128000,64](f32) + bfc

__global__ void k_fc(const unsigned short* __restrict__ A, const float* __restrict__ B,
                     float* __restrict__ part) {
    __shared__ float As[16][68];
    __shared__ float Bs[16][68];
    const int KROW = NB * 128;         // 128000
    int t = threadIdx.x;
    int tx = t & 15, ty = t >> 4;
    int k0b = blockIdx.x * 256;
    float acc[4][4] = {};
    for (int k0 = k0b; k0 < k0b + 256; k0 += 16) {
        int arow = t >> 2, ak = (t & 3) << 2;
        uint2 ua = *(const uint2*)(A + (size_t)arow * KROW + k0 + ak);
        As[ak + 0][arow] = bflo(ua.x);
        As[ak + 1][arow] = bfhi(ua.x);
        As[ak + 2][arow] = bflo(ua.y);
        As[ak + 3][arow] = bfhi(ua.y);
        int bk = t >> 4, bn4 = (t & 15) << 2;
        *(float4*)&Bs[bk][bn4] = *(const float4*)(B + (size_t)(k0 + bk) * NOUT + bn4);
        __syncthreads();
#pragma unroll
        for (int kk = 0; kk < 16; ++kk) {
            float4 a = *(const float4*)&As[kk][ty << 2];
            float4 b = *(const float4*)&Bs[kk][tx << 2];
            acc[0][0] += a.x * b.x; acc[0][1] += a.x * b.y; acc[0][2] += a.x * b.z; acc[0][3] += a.x * b.w;
            acc[1][0] += a.y * b.x; acc[1][1] += a.y * b.y; acc[1][2] += a.y * b.z; acc[1][3] += a.y * b.w;
            acc[2][0] += a.z * b.x; acc[2][1] += a.z * b.y; acc[2][2] += a.z * b.z; acc[2][3] += a.z * b.w;
            acc[3][0] += a.w * b.x; acc[3][1] += a.w * b.y; acc[3][2] += a.w * b.z; acc[3][3] += a.w * b.w;
        }
        __syncthreads();
    }
    float* po = part + (size_t)blockIdx.x * (NG * NOUT);
#pragma unroll
    for (int i = 0; i < 4; ++i) {
        float4 r;
        r.x = acc[i][0]; r.y = acc[i][1]; r.z = acc[i][2]; r.w = acc[i][3];
        *(float4*)&po[((ty << 2) + i) * NOUT + (tx << 2)] = r;
    }
}

__global__ void k_fc_reduce(const float* __restrict__ part, const float* __restrict__ bfc,
                            float* __restrict__ out) {
    int i = blockIdx.x * blockDim.x + threadIdx.x;   // 4096 threads
    float s = bfc[i & 63];
    for (int b = 0; b < FC_SPLIT; ++b) s += part[(size_t)b * (NG * NOUT) + i];
    out[i] = s;
}

// ---------------- driver ----------------

static inline size_t align256(size_t x) { return (x + 255) & ~(size_t)255; }

extern "C" void kernel_launch(void* const* d_in, const int* in_sizes, int n_in,
                              void* d_out, int out_size, void* d_ws, size_t ws_size,
                              hipStream_t stream) {
    const float* x   = (const float*)d_in[0];
    const int*   ei  = (const int*)d_in[1];
    const int*   src = ei;
    const int*   dst = ei + N_EDGES;
    const float* W1  = (const float*)d_in[3];
    const float* b1  = (const float*)d_in[4];
    const float* W2  = (const float*)d_in[5];
    const float* b2  = (const float*)d_in[6];
    const float* W3  = (const float*)d_in[7];
    const float* b3  = (const float*)d_in[8];
    const float* Wfc = (const float*)d_in[9];
    const float* bfc = (const float*)d_in[10];
    float* out = (float*)d_out;

    char* w = (char*)d_ws;
    unsigned short* P0 = (unsigned short*)w; w += align256((size_t)N_NODES * 256 * 2);
    unsigned short* P1 = (unsigned short*)w; w += align256((size_t)N_NODES * 256 * 2);
    unsigned short* P2 = (unsigned short*)w; w += align256((size_t)N_NODES * 256 * 2);
    int* rowptr = (int*)w;      w += align256((size_t)N_NODES * 4);
    int* rowend = (int*)w;      w += align256((size_t)N_NODES * 4);
    float* dinv = (float*)w;    w += align256((size_t)N_NODES * 4);
    int* gcnt = (int*)w;        w += align256((size_t)NG * 4);
    unsigned int* bucket = (unsigned int*)w; w += align256((size_t)NG * BK_CAP * 4);
    unsigned short* colp = (unsigned short*)w; w += align256((size_t)NG * BK_CAP * 2);
    float* fcpart = (float*)w;  w += align256((size_t)FC_SPLIT * NG * NOUT * 4);
    unsigned short* W1t = (unsigned short*)w; w += align256((size_t)128 * 256 * 2);
    unsigned short* W2t = (unsigned short*)w; w += align256((size_t)256 * 256 * 2);
    unsigned short* W3t = (unsigned short*)w; w += align256((size_t)256 * 128 * 2);

    // CSR build
    hipMemsetAsync(gcnt, 0, (size_t)NG * 4, stream);
    k_bucket<<<N_EDGES / 4096, 256, 0, stream>>>(src, dst, gcnt, bucket);
    k_build<<<NG, 1024, 0, stream>>>(gcnt, bucket, rowptr, rowend, dinv, colp);

    // prep: input cast+prescale + 3 weight transposes, one launch
    k_prep<<<8512, 256, 0, stream>>>(x, dinv, P0, W1, W2, W3, W1t, W2t, W3t);

    // layer 1: agg(H=128), gemm1 (tanh+b1+prescale) -> P2 (H=256)
    k_agg<128, false><<<N_NODES / 4, 256, 0, stream>>>(P0, P1, rowptr, rowend, colp, dinv, nullptr);
    k_gemm1<<<N_NODES / 64, 256, 0, stream>>>(P1, W1t, b1, dinv, P2);

    // layer 2: agg(H=256) -> P0; fused gemm2+gemm3 -> P1 (H=128, prescaled)
    k_agg<256, false><<<N_NODES / 4, 256, 0, stream>>>(P2, P0, rowptr, rowend, colp, dinv, nullptr);
    k_gemm23<<<N_NODES / 64, 256, 0, stream>>>(P0, W2t, b2, W3t, dinv, P1);

    // layer 3 aggregation: agg(H=128) + b3 + tanh -> P0
    k_agg<128, true><<<N_NODES / 4, 256, 0, stream>>>(P1, P0, rowptr, rowend, colp, dinv, b3);

    // final FC
    k_fc<<<FC_SPLIT, 256, 0, stream>>>(P0, Wfc, fcpart);
    k_fc_reduce<<<NG * NOUT / 256, 256, 0, stream>>>(fcpart, bfc, out);
}